// Round 3
// baseline (97.059 us; speedup 1.0000x reference)
//
#include <hip/hip_runtime.h>
#include <hip/hip_bf16.h>
#include <stdint.h>

#define NN    4096
#define INF_  256
#define HEADS 4
#define HID   64
#define OUTC  256
#define NEG   0.2f
#define L2E   1.44269504f

#define BI     32
#define JSPLIT 8
#define NJ     (NN / JSPLIT)

typedef short bf16x8 __attribute__((ext_vector_type(8)));
typedef float f32x4  __attribute__((ext_vector_type(4)));

// ---- float <-> order-preserving uint encoding (for atomicMax on f32) ----
__device__ __forceinline__ uint32_t ford(float x){
  uint32_t u = __float_as_uint(x);
  return (u & 0x80000000u) ? ~u : (u | 0x80000000u);
}
__device__ __forceinline__ float funord(uint32_t e){
  uint32_t u = (e & 0x80000000u) ? (e & 0x7fffffffu) : ~e;
  return __uint_as_float(u);
}
__device__ __forceinline__ ushort bf16u(float f){
  __hip_bfloat16 b = __float2bfloat16(f);
  return *reinterpret_cast<ushort*>(&b);
}

// ---- g = h @ W^T per head-tile; emits gT (bf16, [c][j] transposed), slT2/srT2
//      (log2e-scaled scores) and per-head scaled srmax ----
__launch_bounds__(256)
__global__ void k_gemm(const float* __restrict__ hmat, const float* __restrict__ W,
                       const float* __restrict__ aw,
                       short* __restrict__ gT, float* __restrict__ slT2,
                       float* __restrict__ srT2, uint32_t* __restrict__ srmax2){
  __shared__ float hsT[64][68];   // [k][row]
  __shared__ float wsT[64][68];   // [k][col]
  __shared__ float smax_l[16];
  int t  = threadIdx.x;
  int tx = t & 15, ty = t >> 4;
  int r0 = blockIdx.x * 64;
  int cb = blockIdx.y;            // head
  int c0 = cb * 64;
  float acc[4][4] = {};

  for (int k0 = 0; k0 < INF_; k0 += 64){
    int row = t >> 2, kc = (t & 3) * 16;   // transpose-on-load (h tile)
    #pragma unroll
    for (int u = 0; u < 4; u++){
      float4 v = *(const float4*)&hmat[(r0 + row)*INF_ + k0 + kc + 4*u];
      hsT[kc + 4*u + 0][row] = v.x;
      hsT[kc + 4*u + 1][row] = v.y;
      hsT[kc + 4*u + 2][row] = v.z;
      hsT[kc + 4*u + 3][row] = v.w;
    }
    #pragma unroll
    for (int u = 0; u < 4; u++){            // W[c][k] -> wsT[k][c]
      float4 v = *(const float4*)&W[(c0 + row)*INF_ + k0 + kc + 4*u];
      wsT[kc + 4*u + 0][row] = v.x;
      wsT[kc + 4*u + 1][row] = v.y;
      wsT[kc + 4*u + 2][row] = v.z;
      wsT[kc + 4*u + 3][row] = v.w;
    }
    __syncthreads();
    #pragma unroll 8
    for (int k = 0; k < 64; k++){
      float4 hv = *(const float4*)&hsT[k][ty*4];
      float4 wv = *(const float4*)&wsT[k][tx*4];
      float ha[4] = {hv.x, hv.y, hv.z, hv.w};
      float wa[4] = {wv.x, wv.y, wv.z, wv.w};
      #pragma unroll
      for (int a_ = 0; a_ < 4; a_++)
        #pragma unroll
        for (int b_ = 0; b_ < 4; b_++)
          acc[a_][b_] = fmaf(ha[a_], wa[b_], acc[a_][b_]);
    }
    __syncthreads();
  }

  // scores (log2e-scaled)
  float alv[4], arv[4];
  #pragma unroll
  for (int j = 0; j < 4; j++){ alv[j] = aw[tx*4 + j]; arv[j] = aw[64 + tx*4 + j]; }
  float rmax = -3.4e38f;
  #pragma unroll
  for (int qi = 0; qi < 4; qi++){
    int r = r0 + ty*4 + qi;
    float slp = 0.f, srp = 0.f;
    #pragma unroll
    for (int j = 0; j < 4; j++){
      slp = fmaf(acc[qi][j], alv[j], slp);
      srp = fmaf(acc[qi][j], arv[j], srp);
    }
    #pragma unroll
    for (int m = 1; m < 16; m <<= 1){
      slp += __shfl_xor(slp, m, 64);
      srp += __shfl_xor(srp, m, 64);
    }
    if (tx == 0){
      slT2[(size_t)cb*NN + r] = slp * L2E;
      srT2[(size_t)cb*NN + r] = srp * L2E;
      rmax = fmaxf(rmax, srp * L2E);
    }
  }
  if (tx == 0) smax_l[ty] = rmax;

  // transpose acc -> gT (bf16) via LDS reuse
  float* T = (float*)hsT;                    // [c][r] stride 65
  #pragma unroll
  for (int qi = 0; qi < 4; qi++)
    #pragma unroll
    for (int j = 0; j < 4; j++)
      T[(tx*4 + j)*65 + ty*4 + qi] = acc[qi][j];
  __syncthreads();
  if (t == 0){
    float m = smax_l[0];
    #pragma unroll
    for (int i = 1; i < 16; i++) m = fmaxf(m, smax_l[i]);
    atomicMax(srmax2 + cb, ford(m));
  }
  int c = t >> 2, rb = (t & 3) * 16;
  ushort u16[16];
  #pragma unroll
  for (int v = 0; v < 16; v++) u16[v] = bf16u(T[c*65 + rb + v]);
  *(uint4*)&gT[(size_t)(c0 + c)*NN + r0 + rb]     = *(uint4*)&u16[0];
  *(uint4*)&gT[(size_t)(c0 + c)*NN + r0 + rb + 8] = *(uint4*)&u16[8];
}

// ---- fused masked-softmax attention via MFMA, weights built in A-frag layout ----
__launch_bounds__(256, 4)
__global__ void k_attn(const short* __restrict__ gT, const float* __restrict__ slT2,
                       const float* __restrict__ srT2, const uint32_t* __restrict__ srmax2,
                       const int* __restrict__ adj,
                       __hip_bfloat16* __restrict__ num_p, float* __restrict__ den_p){
  int t  = threadIdx.x;
  int h  = t >> 6, l = t & 63;
  int lr = l & 15, lg = l >> 4;        // row-in-tile, k-group
  int i0 = blockIdx.x * BI;
  int jb = blockIdx.y * NJ;
  int js = blockIdx.y;

  float srmaxh = funord(srmax2[h]);
  float d1[2], d2[2];
  #pragma unroll
  for (int m = 0; m < 2; m++){
    float slv = slT2[(size_t)h*NN + i0 + m*16 + lr];
    float x   = slv + srmaxh;
    float msh = fmaxf(x, NEG * x);
    d1[m] = slv - msh;
    d2[m] = NEG * slv - msh;
  }
  f32x4 acc[2][4] = {};
  float denp[2] = {0.f, 0.f};
  const float* srh = srT2 + (size_t)h*NN;
  const short* gTh = gT + (size_t)h*HID*NN;
  const int*   a0p = adj + (size_t)(i0 + lr)*NN;
  const int*   a1p = adj + (size_t)(i0 + 16 + lr)*NN;

  int4 buf0[2][2], buf1[2][2];
  int kk0 = jb + lg*8;

  // prologue: load first step's adjacency into buf0
  buf0[0][0] = *(const int4*)(a0p + kk0);     buf0[0][1] = *(const int4*)(a0p + kk0 + 4);
  buf0[1][0] = *(const int4*)(a1p + kk0);     buf0[1][1] = *(const int4*)(a1p + kk0 + 4);

  #pragma unroll 1
  for (int k0 = jb; k0 < jb + NJ; k0 += 64){
    int kkA = k0 + lg*8;
    int kkB = kkA + 32;
    int kkC = (k0 + 64 < jb + NJ) ? kkA + 64 : jb + lg*8;

    // prefetch step B adjacency
    buf1[0][0] = *(const int4*)(a0p + kkB);   buf1[0][1] = *(const int4*)(a0p + kkB + 4);
    buf1[1][0] = *(const int4*)(a1p + kkB);   buf1[1][1] = *(const int4*)(a1p + kkB + 4);

    // ---- step A: weights from buf0 at kkA ----
    {
      int kk = kkA;
      float4 s0 = *(const float4*)(srh + kk);
      float4 s1 = *(const float4*)(srh + kk + 4);
      float sr8[8]  = {s0.x, s0.y, s0.z, s0.w, s1.x, s1.y, s1.z, s1.w};
      float sr02[8];
      #pragma unroll
      for (int q = 0; q < 8; q++) sr02[q] = NEG * sr8[q];

      bf16x8 B[4];
      #pragma unroll
      for (int n = 0; n < 4; n++)
        B[n] = *(const bf16x8*)(gTh + (size_t)(n*16 + lr)*NN + kk);

      bf16x8 A[2];
      #pragma unroll
      for (int m = 0; m < 2; m++){
        const int* av = (const int*)&buf0[m][0];
        ushort u16[8];
        #pragma unroll
        for (int q = 0; q < 8; q++){
          float e2 = fmaxf(d1[m] + sr8[q], d2[m] + sr02[q]);
          float wv = __builtin_amdgcn_exp2f(e2);
          wv = av[q] ? wv : 0.f;
          denp[m] += wv;
          u16[q] = bf16u(wv);
        }
        A[m] = *(bf16x8*)&u16[0];
      }
      #pragma unroll
      for (int m = 0; m < 2; m++)
        #pragma unroll
        for (int n = 0; n < 4; n++)
          acc[m][n] = __builtin_amdgcn_mfma_f32_16x16x32_bf16(A[m], B[n], acc[m][n], 0, 0, 0);
    }

    // prefetch step C adjacency (next iteration's step A)
    buf0[0][0] = *(const int4*)(a0p + kkC);   buf0[0][1] = *(const int4*)(a0p + kkC + 4);
    buf0[1][0] = *(const int4*)(a1p + kkC);   buf0[1][1] = *(const int4*)(a1p + kkC + 4);

    // ---- step B: weights from buf1 at kkB ----
    {
      int kk = kkB;
      float4 s0 = *(const float4*)(srh + kk);
      float4 s1 = *(const float4*)(srh + kk + 4);
      float sr8[8]  = {s0.x, s0.y, s0.z, s0.w, s1.x, s1.y, s1.z, s1.w};
      float sr02[8];
      #pragma unroll
      for (int q = 0; q < 8; q++) sr02[q] = NEG * sr8[q];

      bf16x8 B[4];
      #pragma unroll
      for (int n = 0; n < 4; n++)
        B[n] = *(const bf16x8*)(gTh + (size_t)(n*16 + lr)*NN + kk);

      bf16x8 A[2];
      #pragma unroll
      for (int m = 0; m < 2; m++){
        const int* av = (const int*)&buf1[m][0];
        ushort u16[8];
        #pragma unroll
        for (int q = 0; q < 8; q++){
          float e2 = fmaxf(d1[m] + sr8[q], d2[m] + sr02[q]);
          float wv = __builtin_amdgcn_exp2f(e2);
          wv = av[q] ? wv : 0.f;
          denp[m] += wv;
          u16[q] = bf16u(wv);
        }
        A[m] = *(bf16x8*)&u16[0];
      }
      #pragma unroll
      for (int m = 0; m < 2; m++)
        #pragma unroll
        for (int n = 0; n < 4; n++)
          acc[m][n] = __builtin_amdgcn_mfma_f32_16x16x32_bf16(A[m], B[n], acc[m][n], 0, 0, 0);
    }
  }

  // num partials (bf16): row = i0+m*16+lg*4+r, col = h*64+n*16+lr
  #pragma unroll
  for (int m = 0; m < 2; m++)
    #pragma unroll
    for (int n = 0; n < 4; n++)
      #pragma unroll
      for (int r = 0; r < 4; r++)
        num_p[((size_t)js*NN + i0 + m*16 + lg*4 + r)*OUTC + h*HID + n*16 + lr] =
            __float2bfloat16(acc[m][n][r]);

  #pragma unroll
  for (int m = 0; m < 2; m++){
    denp[m] += __shfl_xor(denp[m], 16, 64);
    denp[m] += __shfl_xor(denp[m], 32, 64);
  }
  if (lg == 0)
    #pragma unroll
    for (int m = 0; m < 2; m++)
      den_p[((size_t)js*4 + h)*NN + i0 + m*16 + lr] = denp[m];
}

// ---- combine partials: out = sum(num)/sum(den) ----
__global__ void k_comb(const __hip_bfloat16* __restrict__ num_p,
                       const float* __restrict__ den_p, float* __restrict__ out){
  int r = blockIdx.x, c = threadIdx.x;
  int h = c >> 6;
  float s = 0.f, d = 0.f;
  #pragma unroll
  for (int js = 0; js < JSPLIT; js++)
    s += __bfloat162float(num_p[((size_t)js*NN + r)*OUTC + c]);
  #pragma unroll
  for (int js = 0; js < JSPLIT; js++)
    d += den_p[((size_t)js*4 + h)*NN + r];
  out[(size_t)r*OUTC + c] = s / d;
}

extern "C" void kernel_launch(void* const* d_in, const int* in_sizes, int n_in,
                              void* d_out, int out_size, void* d_ws, size_t ws_size,
                              hipStream_t stream){
  const float* hmat = (const float*)d_in[0];
  const int*   adj  = (const int*)d_in[1];     // int32 layout confirmed in r1
  const float* W    = (const float*)d_in[2];
  const float* aw   = (const float*)d_in[3];
  float* out = (float*)d_out;
  char*  ws  = (char*)d_ws;

  // ws layout (bytes), total ~18.6 MB
  uint32_t* srmax2 = (uint32_t*)(ws);                    // 64 B
  float*    slT2   = (float*)(ws + 1024);                // 64 KB   [4][4096]
  float*    srT2   = (float*)(ws + 66560);               // 64 KB   [4][4096]
  short*    gT     = (short*)(ws + 132096);              // 2 MB    [256][4096] bf16
  float*    den_p  = (float*)(ws + 2229248);             // 512 KB  [8][4][4096]
  __hip_bfloat16* num_p = (__hip_bfloat16*)(ws + 2753536); // 16.75 MB [8][4096][256]

  hipMemsetAsync(ws, 0, 64, stream);   // srmax2 init (0 < ford(any float))
  hipLaunchKernelGGL(k_gemm, dim3(64, 4), dim3(256), 0, stream,
                     hmat, W, aw, gT, slT2, srT2, srmax2);
  hipLaunchKernelGGL(k_attn, dim3(NN/BI, JSPLIT), dim3(256), 0, stream,
                     gT, slT2, srT2, srmax2, adj, num_p, den_p);
  hipLaunchKernelGGL(k_comb, dim3(NN), dim3(256), 0, stream, num_p, den_p, out);
}

// Round 4
// 78.656 us; speedup vs baseline: 1.2340x; 1.2340x over previous
//
#include <hip/hip_runtime.h>
#include <hip/hip_bf16.h>
#include <stdint.h>

#define NN    4096
#define INF_  256
#define HEADS 4
#define HID   64
#define OUTC  256
#define NEG   0.2f
#define L2E   1.44269504f

#define BI     32
#define JSPLIT 8
#define NJ     (NN / JSPLIT)

typedef short bf16x8 __attribute__((ext_vector_type(8)));
typedef float f32x4  __attribute__((ext_vector_type(4)));

// ---- float <-> order-preserving uint encoding (for atomicMax on f32) ----
__device__ __forceinline__ uint32_t ford(float x){
  uint32_t u = __float_as_uint(x);
  return (u & 0x80000000u) ? ~u : (u | 0x80000000u);
}
__device__ __forceinline__ float funord(uint32_t e){
  uint32_t u = (e & 0x80000000u) ? (e & 0x7fffffffu) : ~e;
  return __uint_as_float(u);
}
__device__ __forceinline__ ushort bf16u(float f){
  __hip_bfloat16 b = __float2bfloat16(f);
  return *reinterpret_cast<ushort*>(&b);
}

// ---- adjacency int32 [4096][4096] -> bitmask [4096][128] uint32 ----
// bit b of bm[i*128+w] = (adj[i*4096 + w*32 + b] != 0)
__global__ void k_pack(const int* __restrict__ adj, uint32_t* __restrict__ bm){
  __shared__ ushort sh[256];
  int i = blockIdx.x;
  int t = threadIdx.x;
  const int* row = adj + (size_t)i*NN + t*16;
  uint32_t b = 0;
  #pragma unroll
  for (int u = 0; u < 4; u++){
    int4 v = *(const int4*)(row + u*4);
    b |= (v.x ? 1u : 0u) << (u*4 + 0);
    b |= (v.y ? 1u : 0u) << (u*4 + 1);
    b |= (v.z ? 1u : 0u) << (u*4 + 2);
    b |= (v.w ? 1u : 0u) << (u*4 + 3);
  }
  sh[t] = (ushort)b;
  __syncthreads();
  if (t < 128)
    bm[(size_t)i*128 + t] = (uint32_t)sh[2*t] | ((uint32_t)sh[2*t + 1] << 16);
}

// ---- g = h @ W^T per head-tile; emits gT (bf16, [c][j] transposed), slT2/srT2
//      (log2e-scaled scores) and per-head scaled srmax ----
__launch_bounds__(256)
__global__ void k_gemm(const float* __restrict__ hmat, const float* __restrict__ W,
                       const float* __restrict__ aw,
                       short* __restrict__ gT, float* __restrict__ slT2,
                       float* __restrict__ srT2, uint32_t* __restrict__ srmax2){
  __shared__ float hsT[64][68];   // [k][row]
  __shared__ float wsT[64][68];   // [k][col]
  __shared__ float smax_l[16];
  int t  = threadIdx.x;
  int tx = t & 15, ty = t >> 4;
  int r0 = blockIdx.x * 64;
  int cb = blockIdx.y;            // head
  int c0 = cb * 64;
  float acc[4][4] = {};

  for (int k0 = 0; k0 < INF_; k0 += 64){
    int row = t >> 2, kc = (t & 3) * 16;   // transpose-on-load (h tile)
    #pragma unroll
    for (int u = 0; u < 4; u++){
      float4 v = *(const float4*)&hmat[(r0 + row)*INF_ + k0 + kc + 4*u];
      hsT[kc + 4*u + 0][row] = v.x;
      hsT[kc + 4*u + 1][row] = v.y;
      hsT[kc + 4*u + 2][row] = v.z;
      hsT[kc + 4*u + 3][row] = v.w;
    }
    #pragma unroll
    for (int u = 0; u < 4; u++){            // W[c][k] -> wsT[k][c]
      float4 v = *(const float4*)&W[(c0 + row)*INF_ + k0 + kc + 4*u];
      wsT[kc + 4*u + 0][row] = v.x;
      wsT[kc + 4*u + 1][row] = v.y;
      wsT[kc + 4*u + 2][row] = v.z;
      wsT[kc + 4*u + 3][row] = v.w;
    }
    __syncthreads();
    #pragma unroll 8
    for (int k = 0; k < 64; k++){
      float4 hv = *(const float4*)&hsT[k][ty*4];
      float4 wv = *(const float4*)&wsT[k][tx*4];
      float ha[4] = {hv.x, hv.y, hv.z, hv.w};
      float wa[4] = {wv.x, wv.y, wv.z, wv.w};
      #pragma unroll
      for (int a_ = 0; a_ < 4; a_++)
        #pragma unroll
        for (int b_ = 0; b_ < 4; b_++)
          acc[a_][b_] = fmaf(ha[a_], wa[b_], acc[a_][b_]);
    }
    __syncthreads();
  }

  // scores (log2e-scaled)
  float alv[4], arv[4];
  #pragma unroll
  for (int j = 0; j < 4; j++){ alv[j] = aw[tx*4 + j]; arv[j] = aw[64 + tx*4 + j]; }
  float rmax = -3.4e38f;
  #pragma unroll
  for (int qi = 0; qi < 4; qi++){
    int r = r0 + ty*4 + qi;
    float slp = 0.f, srp = 0.f;
    #pragma unroll
    for (int j = 0; j < 4; j++){
      slp = fmaf(acc[qi][j], alv[j], slp);
      srp = fmaf(acc[qi][j], arv[j], srp);
    }
    #pragma unroll
    for (int m = 1; m < 16; m <<= 1){
      slp += __shfl_xor(slp, m, 64);
      srp += __shfl_xor(srp, m, 64);
    }
    if (tx == 0){
      slT2[(size_t)cb*NN + r] = slp * L2E;
      srT2[(size_t)cb*NN + r] = srp * L2E;
      rmax = fmaxf(rmax, srp * L2E);
    }
  }
  if (tx == 0) smax_l[ty] = rmax;

  // transpose acc -> gT (bf16) via LDS reuse
  float* T = (float*)hsT;                    // [c][r] stride 65
  #pragma unroll
  for (int qi = 0; qi < 4; qi++)
    #pragma unroll
    for (int j = 0; j < 4; j++)
      T[(tx*4 + j)*65 + ty*4 + qi] = acc[qi][j];
  __syncthreads();
  if (t == 0){
    float m = smax_l[0];
    #pragma unroll
    for (int i = 1; i < 16; i++) m = fmaxf(m, smax_l[i]);
    atomicMax(srmax2 + cb, ford(m));
  }
  int c = t >> 2, rb = (t & 3) * 16;
  ushort u16[16];
  #pragma unroll
  for (int v = 0; v < 16; v++) u16[v] = bf16u(T[c*65 + rb + v]);
  *(uint4*)&gT[(size_t)(c0 + c)*NN + r0 + rb]     = *(uint4*)&u16[0];
  *(uint4*)&gT[(size_t)(c0 + c)*NN + r0 + rb + 8] = *(uint4*)&u16[8];
}

// ---- fused masked-softmax attention via MFMA; adjacency+sr staged in LDS,
//      gT register-double-buffered (only in-loop memory stream, L2-resident) ----
__launch_bounds__(256, 4)
__global__ void k_attn(const short* __restrict__ gT, const float* __restrict__ slT2,
                       const float* __restrict__ srT2, const uint32_t* __restrict__ srmax2,
                       const uint32_t* __restrict__ bm,
                       __hip_bfloat16* __restrict__ num_p, float* __restrict__ den_p){
  __shared__ uint32_t bmlds[32 * 17];   // [row][word] stride 17 -> conflict-free
  __shared__ float    srs[4][512];      // [head][j - jb], log2e-scaled
  int t  = threadIdx.x;
  int h  = t >> 6, l = t & 63;
  int lr = l & 15, lg = l >> 4;
  int i0 = blockIdx.x * BI;
  int jb = blockIdx.y * NJ;
  int js = blockIdx.y;

  // stage sr slice + bitmask tile
  #pragma unroll
  for (int u = 0; u < 2; u++){
    int id = t + u*256;
    int hh = id >> 7, jj = (id & 127) * 4;
    *(float4*)&srs[hh][jj] = *(const float4*)&srT2[(size_t)hh*NN + jb + jj];
    int r = id >> 4, w = id & 15;
    bmlds[r*17 + w] = bm[(size_t)(i0 + r)*128 + (jb >> 5) + w];
  }

  float srmaxh = funord(srmax2[h]);
  float d1[2], d2[2];
  #pragma unroll
  for (int m = 0; m < 2; m++){
    float slv = slT2[(size_t)h*NN + i0 + m*16 + lr];
    float x   = slv + srmaxh;
    float msh = fmaxf(x, NEG * x);
    d1[m] = slv - msh;
    d2[m] = NEG * slv - msh;
  }
  __syncthreads();

  f32x4 acc[2][4] = {};
  float denp[2] = {0.f, 0.f};
  const short* gTh = gT + (size_t)h*HID*NN;

  bf16x8 B0[4], B1[4];
  #pragma unroll
  for (int n = 0; n < 4; n++)
    B0[n] = *(const bf16x8*)(gTh + (size_t)(n*16 + lr)*NN + jb + lg*8);

  auto step = [&](int s, bf16x8* Bc, bf16x8* Bn){
    int koff = s*32 + lg*8;
    int kn   = (s < 15) ? koff + 32 : lg*8;   // last prefetch is a dummy wrap
    #pragma unroll
    for (int n = 0; n < 4; n++)
      Bn[n] = *(const bf16x8*)(gTh + (size_t)(n*16 + lr)*NN + jb + kn);

    float4 s0 = *(const float4*)&srs[h][koff];
    float4 s1 = *(const float4*)&srs[h][koff + 4];
    float sr8[8] = {s0.x, s0.y, s0.z, s0.w, s1.x, s1.y, s1.z, s1.w};
    float sr02[8];
    #pragma unroll
    for (int q = 0; q < 8; q++) sr02[q] = NEG * sr8[q];

    uint32_t wrd[2];
    wrd[0] = bmlds[lr*17 + s];
    wrd[1] = bmlds[(16 + lr)*17 + s];

    bf16x8 A[2];
    #pragma unroll
    for (int m = 0; m < 2; m++){
      uint32_t bits = (wrd[m] >> (lg*8)) & 0xffu;
      ushort u16[8];
      #pragma unroll
      for (int q = 0; q < 8; q++){
        float e2 = fmaxf(d1[m] + sr8[q], d2[m] + sr02[q]);
        float wv = __builtin_amdgcn_exp2f(e2);
        wv = (bits & (1u << q)) ? wv : 0.f;
        denp[m] += wv;
        u16[q] = bf16u(wv);
      }
      A[m] = *(bf16x8*)&u16[0];
    }
    #pragma unroll
    for (int m = 0; m < 2; m++)
      #pragma unroll
      for (int n = 0; n < 4; n++)
        acc[m][n] = __builtin_amdgcn_mfma_f32_16x16x32_bf16(A[m], Bc[n], acc[m][n], 0, 0, 0);
  };

  #pragma unroll 1
  for (int s = 0; s < 16; s += 2){
    step(s,     B0, B1);
    step(s + 1, B1, B0);
  }

  // num partials (bf16): row = i0+m*16+lg*4+r, col = h*64+n*16+lr
  #pragma unroll
  for (int m = 0; m < 2; m++)
    #pragma unroll
    for (int n = 0; n < 4; n++)
      #pragma unroll
      for (int r = 0; r < 4; r++)
        num_p[((size_t)js*NN + i0 + m*16 + lg*4 + r)*OUTC + h*HID + n*16 + lr] =
            __float2bfloat16(acc[m][n][r]);

  #pragma unroll
  for (int m = 0; m < 2; m++){
    denp[m] += __shfl_xor(denp[m], 16, 64);
    denp[m] += __shfl_xor(denp[m], 32, 64);
  }
  if (lg == 0)
    #pragma unroll
    for (int m = 0; m < 2; m++)
      den_p[((size_t)js*4 + h)*NN + i0 + m*16 + lr] = denp[m];
}

// ---- combine partials: out = sum(num)/sum(den) ----
__global__ void k_comb(const __hip_bfloat16* __restrict__ num_p,
                       const float* __restrict__ den_p, float* __restrict__ out){
  int r = blockIdx.x, c = threadIdx.x;
  int h = c >> 6;
  float s = 0.f, d = 0.f;
  #pragma unroll
  for (int js = 0; js < JSPLIT; js++)
    s += __bfloat162float(num_p[((size_t)js*NN + r)*OUTC + c]);
  #pragma unroll
  for (int js = 0; js < JSPLIT; js++)
    d += den_p[((size_t)js*4 + h)*NN + r];
  out[(size_t)r*OUTC + c] = s / d;
}

extern "C" void kernel_launch(void* const* d_in, const int* in_sizes, int n_in,
                              void* d_out, int out_size, void* d_ws, size_t ws_size,
                              hipStream_t stream){
  const float* hmat = (const float*)d_in[0];
  const int*   adj  = (const int*)d_in[1];     // int32 layout confirmed in r1
  const float* W    = (const float*)d_in[2];
  const float* aw   = (const float*)d_in[3];
  float* out = (float*)d_out;
  char*  ws  = (char*)d_ws;

  // ws layout (bytes), total ~21.6 MB
  uint32_t* srmax2 = (uint32_t*)(ws);                      // 64 B
  float*    slT2   = (float*)(ws + 1024);                  // 64 KB   [4][4096]
  float*    srT2   = (float*)(ws + 66560);                 // 64 KB   [4][4096]
  short*    gT     = (short*)(ws + 132096);                // 2 MB    [256][4096] bf16
  float*    den_p  = (float*)(ws + 2229248);               // 512 KB  [8][4][4096]
  __hip_bfloat16* num_p = (__hip_bfloat16*)(ws + 2753536); // 16.75 MB [8][4096][256]
  uint32_t* bmask  = (uint32_t*)(ws + 19530752);           // 2 MB    [4096][128]

  hipMemsetAsync(ws, 0, 64, stream);   // srmax2 init (0 < ford(any float))
  hipLaunchKernelGGL(k_pack, dim3(NN), dim3(256), 0, stream, adj, bmask);
  hipLaunchKernelGGL(k_gemm, dim3(64, 4), dim3(256), 0, stream,
                     hmat, W, aw, gT, slT2, srT2, srmax2);
  hipLaunchKernelGGL(k_attn, dim3(NN/BI, JSPLIT), dim3(256), 0, stream,
                     gT, slT2, srT2, srmax2, bmask, num_p, den_p);
  hipLaunchKernelGGL(k_comb, dim3(NN), dim3(256), 0, stream, num_p, den_p, out);
}